// Round 21
// baseline (151.945 us; speedup 1.0000x reference)
//
#include <hip/hip_runtime.h>
#include <hip/hip_bf16.h>
#include <cmath>

#define NB 4
#define NNEG 33
#define NN 10000
#define NE 100000
#define NW 3
#define DD 64
#define NL 3
#define NR 200
#define NFL 2
#define NFFN 256
#define LN_EPS 1e-5f
#define RPB 2
#define XSZ (NB*NN*DD)
#define LCAP 2048
#define SLOTS 64
#define L0ECAP 1024
#define L0NCAP 512

// ---- ws layout (float offsets) ----
#define OFF_QUERY 0
#define OFF_H0    256
#define OFF_TSW   288
#define OFF_MINT  448
#define OFF_RELI  512                                 // NL*NR*NB*DD
#define OFF_LINT  (OFF_RELI + NL*NR*NB*DD)            // NL*2*DD*DD
#define OFF_X     (OFF_LINT + NL*2*DD*DD)             // NW*XSZ (x1, sparse-valid)
#define OFF_X2    (OFF_X + NW*XSZ)                    // NW*XSZ (x2, needed-valid)
#define OFF_TOK   (OFF_X2 + NW*XSZ)                   // NB*NNEG*NW*DD (unused now)
#define OFF_YC    (OFF_TOK + NB*NNEG*NW*DD)           // 64 yc + 64 hcx
// int offsets
#define IOFF_FLG  (OFF_YC + 128)                      // NW*NN words (byte per (n,b))
#define IOFF_NEED (IOFF_FLG + NW*NN)                  // NW*NN words
#define IOFF_CNT  (IOFF_NEED + NW*NN)                 // NW
#define IOFF_LIST (IOFF_CNT + NW)                     // NW*LCAP
#define IOFF_L0EC (IOFF_LIST + NW*LCAP)               // NW
#define IOFF_L0NC (IOFF_L0EC + NW)                    // NW
#define IOFF_L0EL (((IOFF_L0NC + NW) + 3) & ~3)       // NW*L0ECAP*4, 16B aligned
#define IOFF_L0ND (IOFF_L0EL + NW*L0ECAP*4)           // NW*L0NCAP
#define IOFF_TAILF (IOFF_L0ND + NW*L0NCAP)            // NN words (b-mask, shared w)
#define IOFF_LIDX (IOFF_TAILF + NN)                   // NW*NN (list index per needed node)
#define IOFF_DEG  (IOFF_LIDX + NW*NN)                 // NW*LCAP cursors
#define IOFF_REC2 (((IOFF_DEG + NW*LCAP) + 3) & ~3)   // NW*LCAP*SLOTS*4 ints, 16B aligned

// ---------------- prep (+ yconst/hcx) + transpose + tailf zero ----------------
__global__ void k_prep(const int* __restrict__ qt, const float* __restrict__ qemb,
                       const float* __restrict__ linw, const float* __restrict__ linb,
                       const float* __restrict__ lns, const float* __restrict__ lnb,
                       float* __restrict__ ws) {
  int bx = blockIdx.x;
  if (bx >= 97) {  // zero tailf
    int idx = (bx - 97) * 256 + threadIdx.x;
    if (idx < NN) ((int*)ws)[IOFF_TAILF + idx] = 0;
    return;
  }
  if (bx > 0) {  // transpose: linT[l][k][c] = lin_w[l][c][k]
    int idx = (bx - 1) * 256 + threadIdx.x;
    if (idx < NL * 2 * DD * DD) {
      int l = idx / (2 * DD * DD), r = idx % (2 * DD * DD), k = r / DD, c = r % DD;
      ws[OFF_LINT + idx] = linw[(l * DD + c) * 2 * DD + k];
    }
    return;
  }
  int tid = threadIdx.x;
  if (tid < NB * DD) {
    int b = tid / DD, d = tid % DD;
    int h0 = qt[(b * NNEG + 0) * 3 + 0];
    bool itn = true;
    for (int j = 1; j < NNEG; ++j) itn = itn && (qt[(b * NNEG + j) * 3 + 0] == h0);
    int r0 = qt[(b * NNEG + 0) * 3 + 1] + (itn ? 0 : NR / 2);
    ws[OFF_QUERY + b * DD + d] = qemb[r0 * DD + d];
    if (d == 0) {
      int t0 = qt[(b * NNEG + 0) * 3 + 2];
      ((int*)ws)[OFF_H0 + b] = itn ? h0 : t0;
    }
  }
  if (tid < NB * NNEG) {
    int b = tid / NNEG, j = tid % NNEG;
    int h0 = qt[(b * NNEG + 0) * 3 + 0];
    bool itn = true;
    for (int jj = 1; jj < NNEG; ++jj) itn = itn && (qt[(b * NNEG + jj) * 3 + 0] == h0);
    int h = qt[(b * NNEG + j) * 3 + 0], t = qt[(b * NNEG + j) * 3 + 2];
    ((int*)ws)[OFF_TSW + tid] = itn ? t : h;
  }
  if (tid == 0) ((int*)ws)[OFF_MINT] = 0x7fffffff;
  if (tid < 64) {
    int d = tid;
    float v = linb[d];  // l = 0 bias
    float s = v;
    for (int m = 1; m < 64; m <<= 1) s += __shfl_xor(s, m);
    float mean = s * (1.f / 64.f);
    float cv = v - mean;
    float vv = cv * cv;
    for (int m = 1; m < 64; m <<= 1) vv += __shfl_xor(vv, m);
    vv *= (1.f / 64.f);
    float y = cv * __frsqrt_rn(vv + LN_EPS) * lns[d] + lnb[d];
    y = fmaxf(y, 0.f);
    ws[OFF_YC + d] = y;
    const float* wr = linw + (size_t)DD * 2 * DD + (size_t)d * 2 * DD;  // l=1 row d
    float acc = 0.f;
    for (int k = 0; k < 64; ++k) acc = fmaf(__shfl(y, k), wr[k], acc);
    ws[OFF_YC + 64 + d] = acc;
  }
}

// ---------------- min over edge_time[0] + zero need/flg/deg/counters + tail mark ------
__global__ void k_mint(const int* __restrict__ etime, float* __restrict__ ws) {
  int i = blockIdx.x * blockDim.x + threadIdx.x;
  int* wsi = (int*)ws;
  if (i < NW * NN) wsi[IOFF_NEED + i] = 0;
  if (i < NW * NN) wsi[IOFF_FLG + i] = 0;
  if (i < NW * LCAP) wsi[IOFF_DEG + i] = 0;
  if (i < NW) {
    wsi[IOFF_CNT + i] = 0;
    wsi[IOFF_L0EC + i] = 0;
    wsi[IOFF_L0NC + i] = 0;
  }
  if (i < NB * NNEG) {  // mark tailflag (tailf zeroed in k_prep)
    int b = i / NNEG;
    int t = wsi[OFF_TSW + i];
    atomicOr((unsigned int*)&wsi[IOFF_TAILF + t], 1u << (b * 8));
  }
  int v = (i < NE) ? etime[i] : 0x7fffffff;
  for (int m = 1; m < 64; m <<= 1) v = min(v, __shfl_xor(v, m));
  if ((threadIdx.x & 63) == 0) atomicMin(&wsi[OFF_MINT], v);
}

// ------- merged: rel (bx<50) | single edge pass: edge0 + needscan (50..440) ----------
__global__ void k_relhist(const float* __restrict__ rlw, const float* __restrict__ rlb,
                          const int* __restrict__ eidx, const int* __restrict__ etype,
                          const int* __restrict__ etime, const float* __restrict__ eweight,
                          float* __restrict__ ws) {
  int bx = blockIdx.x;
  int* wsi = (int*)ws;
  if (bx < 50) {  // ---- rel: l = blockIdx.y ----
    int l = blockIdx.y;
    int rd = bx * 256 + threadIdx.x;
    const float4* wrow = (const float4*)(rlw + ((size_t)(l * NR * DD + rd)) * DD);
    float4 wreg[16];
#pragma unroll
    for (int kk = 0; kk < 16; ++kk) wreg[kk] = wrow[kk];
    float bias = rlb[l * NR * DD + rd];
    int r = rd >> 6, d = rd & 63;
    for (int b = 0; b < NB; ++b) {
      const float4* q4 = (const float4*)(ws + OFF_QUERY + b * DD);
      float acc = 0.f;
#pragma unroll
      for (int kk = 0; kk < 16; ++kk) {
        float4 q = q4[kk];
        acc += q.x * wreg[kk].x + q.y * wreg[kk].y + q.z * wreg[kk].z + q.w * wreg[kk].w;
      }
      ws[OFF_RELI + (size_t)(l * NR + r) * (NB * DD) + b * DD + d] = acc + bias;
    }
    return;
  }
  int w = blockIdx.y;
  unsigned int* flgw = (unsigned int*)(wsi + IOFF_FLG) + (size_t)w * NN;
  unsigned int* needw = (unsigned int*)(wsi + IOFF_NEED) + (size_t)w * NN;
  int* l0nc = wsi + IOFF_L0NC + w;
  int* l0nd = wsi + IOFF_L0ND + w * L0NCAP;
  int* cnt = wsi + IOFF_CNT + w;
  int* list = wsi + IOFF_LIST + (size_t)w * LCAP;
  int* lidx = wsi + IOFF_LIDX + (size_t)w * NN;
  if (bx == 50) {  // one-offs: h0 flag init + tails need-init
    if (threadIdx.x < NB) {
      int b = threadIdx.x;
      int h0b = wsi[OFF_H0 + b];
      unsigned int old = atomicOr(&flgw[h0b], 1u << (b * 8));
      if (old == 0u) {
        int p = atomicAdd(l0nc, 1);
        if (p < L0NCAP) l0nd[p] = h0b;
      }
    }
    if (threadIdx.x >= 64 && threadIdx.x < 64 + NB * NNEG) {
      int i = threadIdx.x - 64;
      int b = i / NNEG;
      int t = wsi[OFF_TSW + i];
      unsigned int old = atomicOr(&needw[t], 1u << (b * 8));
      if (old == 0u) {
        int p = atomicAdd(cnt, 1);
        if (p < LCAP) {
          list[p] = t;
          lidx[t] = p;
        }
      }
    }
  }
  int e = (bx - 50) * 256 + threadIdx.x;
  if (e >= NE) return;
  int src = eidx[(w * 2 + 0) * NE + e];
  int dst = eidx[(w * 2 + 1) * NE + e];
  // ---- edge0: src in {h0} ----
  int h00 = wsi[OFF_H0 + 0], h01 = wsi[OFF_H0 + 1];
  int h02 = wsi[OFF_H0 + 2], h03 = wsi[OFF_H0 + 3];
  int mask =
      (src == h00) | ((src == h01) << 1) | ((src == h02) << 2) | ((src == h03) << 3);
  if (mask) {
    unsigned int fm = ((mask & 1) ? 0x1u : 0u) | ((mask & 2) ? 0x100u : 0u) |
                      ((mask & 4) ? 0x10000u : 0u) | ((mask & 8) ? 0x1000000u : 0u);
    unsigned int old = atomicOr(&flgw[dst], fm);
    if (old == 0u) {
      int p = atomicAdd(l0nc, 1);
      if (p < L0NCAP) l0nd[p] = dst;
    }
    float dt = (float)etime[w * NE + e] - (float)wsi[OFF_MINT];
    int p = atomicAdd(wsi + IOFF_L0EC + w, 1);
    if (p < L0ECAP) {
      int4 ent;
      ent.x = dst;
      ent.y = etype[w * NE + e] | (mask << 16);
      ent.z = __float_as_int(dt);
      ent.w = __float_as_int(eweight[w * NE + e]);
      ((int4*)(wsi + IOFF_L0EL))[(size_t)w * L0ECAP + p] = ent;
    }
  }
  // ---- needscan: dst is tail -> mark src needed ----
  unsigned int tf = ((const unsigned int*)(wsi + IOFF_TAILF))[dst];
  if (tf) {
    unsigned int old = atomicOr(&needw[src], tf);
    if (old == 0u) {
      int p = atomicAdd(cnt, 1);
      if (p < LCAP) {
        list[p] = src;
        lidx[src] = p;
      }
    }
  }
}

// ---------------- merged: slot-list build (bx<391) | l0 compute (bx>=391) -------------
__global__ __launch_bounds__(256) void k_build(const int* __restrict__ eidx,
                                               const int* __restrict__ etype,
                                               const int* __restrict__ etime,
                                               const float* __restrict__ eweight,
                                               const float* __restrict__ tw,
                                               const float* __restrict__ tb,
                                               const float* __restrict__ linb,
                                               const float* __restrict__ lns,
                                               const float* __restrict__ lnb,
                                               float* __restrict__ ws) {
  __shared__ float aggbuf[4][NB][DD];
  int bx = blockIdx.x, w = blockIdx.y;
  int* wsi = (int*)ws;
  if (bx < 391) {  // ---- append needed-dst edges into per-node slot lists ----
    int e = bx * 256 + threadIdx.x;
    if (e >= NE) return;
    int dst = eidx[(w * 2 + 1) * NE + e];
    unsigned int nd = ((const unsigned int*)(wsi + IOFF_NEED))[(size_t)w * NN + dst];
    if (nd == 0u) return;
    int li = wsi[IOFF_LIDX + (size_t)w * NN + dst];
    int slot = atomicAdd(&wsi[IOFF_DEG + (size_t)w * LCAP + li], 1);
    if (slot < SLOTS) {
      float dt = (float)etime[w * NE + e] - (float)wsi[OFF_MINT];
      int4 rec;
      rec.x = eidx[(w * 2 + 0) * NE + e];
      rec.y = etype[w * NE + e];
      rec.z = __float_as_int(dt);
      rec.w = __float_as_int(eweight[w * NE + e]);
      ((int4*)(wsi + IOFF_REC2))[((size_t)w * LCAP + li) * SLOTS + slot] = rec;
    }
    return;
  }
  // ---- l0 compute: worklist of flagged nodes -> agg + gemm -> X1 ----
  int lane = threadIdx.x & 63;
  int wv = threadIdx.x >> 6;
  int b = lane >> 4;
  int q4i = lane & 15;
  int cnt = wsi[IOFF_L0NC + w];
  if (cnt > L0NCAP) cnt = L0NCAP;
  int idx = (bx - 391) * 4 + wv;
  if (idx >= cnt) return;  // no barriers below
  int n = wsi[IOFF_L0ND + w * L0NCAP + idx];
  unsigned int flagword = ((const unsigned int*)(wsi + IOFF_FLG))[(size_t)w * NN + n];
  int h0b = wsi[OFF_H0 + b];
  float4 q4b = ((const float4*)(ws + OFF_QUERY))[lane];
  float4 acc;
  if (n == h0b) acc = q4b;
  else { acc.x = 0.f; acc.y = 0.f; acc.z = 0.f; acc.w = 0.f; }
  int ec = wsi[IOFF_L0EC + w];
  if (ec > L0ECAP) ec = L0ECAP;
  const int4* el = ((const int4*)(wsi + IOFF_L0EL)) + (size_t)w * L0ECAP;
  const float4* RELI4 = (const float4*)(ws + OFF_RELI);  // l = 0
  const float4* TW4 = (const float4*)tw;
  const float4* TB4 = (const float4*)tb;
  for (int j = 0; j < ec; ++j) {
    int4 ent = el[j];
    if (ent.x != n) continue;
    int et = ent.y & 0xffff;
    int mask = ent.y >> 16;
    float dtf = __int_as_float(ent.z);
    float wgt = ((mask >> b) & 1) ? __int_as_float(ent.w) : 0.f;
    float4 r4 = RELI4[et * 64 + lane];
    float4 w4 = TW4[et * 16 + q4i];
    float4 b4 = TB4[et * 16 + q4i];
    acc.x = fmaf(q4b.x * r4.x, __cosf(fmaf(dtf, w4.x, b4.x)) * wgt, acc.x);
    acc.y = fmaf(q4b.y * r4.y, __cosf(fmaf(dtf, w4.y, b4.y)) * wgt, acc.y);
    acc.z = fmaf(q4b.z * r4.z, __cosf(fmaf(dtf, w4.z, b4.z)) * wgt, acc.z);
    acc.w = fmaf(q4b.w * r4.w, __cosf(fmaf(dtf, w4.w, b4.w)) * wgt, acc.w);
  }
  *(float4*)&aggbuf[wv][b][q4i * 4] = acc;
  int c = lane;
  const float* WT = ws + OFF_LINT;  // l = 0
  float* X1 = ws + OFF_X + (size_t)w * XSZ;
  float sc = lns[c], bc = lnb[c];
#pragma unroll 1
  for (int r = 0; r < NB; ++r) {
    if (!((flagword >> (r * 8)) & 0xffu)) continue;
    int h0r = wsi[OFF_H0 + r];
    float a = linb[c];
    if (n == h0r) {
      const float4* q4 = (const float4*)(ws + OFF_QUERY + r * DD);
      for (int kk = 0; kk < 16; ++kk) {
        float4 qv = q4[kk];
        a = fmaf(qv.x, WT[(4 * kk + 0) * DD + c], a);
        a = fmaf(qv.y, WT[(4 * kk + 1) * DD + c], a);
        a = fmaf(qv.z, WT[(4 * kk + 2) * DD + c], a);
        a = fmaf(qv.w, WT[(4 * kk + 3) * DD + c], a);
      }
    }
#pragma unroll 8
    for (int k = 0; k < DD; ++k)
      a = fmaf(aggbuf[wv][r][k], WT[(DD + k) * DD + c], a);
    float s = a;
    for (int m = 1; m < 64; m <<= 1) s += __shfl_xor(s, m);
    float mean = s * (1.f / 64.f);
    float cv = a - mean;
    float vv = cv * cv;
    for (int m = 1; m < 64; m <<= 1) vv += __shfl_xor(vv, m);
    vv *= (1.f / 64.f);
    float y = cv * __frsqrt_rn(vv + LN_EPS) * sc + bc;
    y = fmaxf(y, 0.f);
    float xo = (n == h0r) ? ws[OFF_QUERY + r * DD + c] : 0.f;
    X1[((size_t)n * NB + r) * DD + c] = xo + y;
  }
}

// ---------------- l1 fused, worklist-driven -> X2 (slot lists) ----------------
__global__ __launch_bounds__(256) void k_l1(const float* __restrict__ tw,
                                            const float* __restrict__ tb,
                                            const float* __restrict__ linb,
                                            const float* __restrict__ lns,
                                            const float* __restrict__ lnb,
                                            float* __restrict__ ws) {
  __shared__ float aggbuf[4][NB][DD];
  int w = blockIdx.y;
  const int* wsi = (const int*)ws;
  int cnt = wsi[IOFF_CNT + w];
  if (cnt > LCAP) cnt = LCAP;
  int wv = threadIdx.x >> 6;
  int idx = blockIdx.x * 4 + wv;
  if (idx >= cnt) return;  // per-wave exit; no barriers
  int n = wsi[IOFF_LIST + (size_t)w * LCAP + idx];
  int lane = threadIdx.x & 63;
  int b = lane >> 4;
  int q4i = lane & 15;
  unsigned int needw = ((const unsigned int*)(wsi + IOFF_NEED))[(size_t)w * NN + n];
  int dg = wsi[IOFF_DEG + (size_t)w * LCAP + idx];
  dg = __builtin_amdgcn_readfirstlane(dg > SLOTS ? SLOTS : dg);
  const int4* recs = ((const int4*)(wsi + IOFF_REC2)) + ((size_t)w * LCAP + idx) * SLOTS;
  const float4* X14 = (const float4*)(ws + OFF_X + (size_t)w * XSZ);
  const float4* RELI4 = (const float4*)(ws + OFF_RELI) + (size_t)1 * NR * 64;
  const float4* TW4 = (const float4*)(tw + (size_t)1 * NR * DD);
  const float4* TB4 = (const float4*)(tb + (size_t)1 * NR * DD);
  const unsigned int* xflg = (const unsigned int*)(wsi + IOFF_FLG) + (size_t)w * NN;
  int h0b = wsi[OFF_H0 + b];
  float4 q4b = ((const float4*)(ws + OFF_QUERY))[lane];
  float4 yc4 = ((const float4*)(ws + OFF_YC))[q4i];
  float4 acc;
  if (n == h0b) acc = q4b;
  else { acc.x = 0.f; acc.y = 0.f; acc.z = 0.f; acc.w = 0.f; }
  for (int j = 0; j < dg; ++j) {
    int4 rec = recs[j];
    int src = rec.x, et = rec.y;
    float dtf = __int_as_float(rec.z), wgt = __int_as_float(rec.w);
    unsigned int fw = xflg[src];
    float4 x4;
    if (fw == 0u) {
      x4 = yc4;
    } else {
      int myf = (fw >> (b * 8)) & 0xff;
      if (myf) x4 = X14[(size_t)src * 64 + lane];
      else x4 = yc4;
    }
    float4 r4 = RELI4[et * 64 + lane];
    float4 w4 = TW4[et * 16 + q4i];
    float4 b4 = TB4[et * 16 + q4i];
    acc.x = fmaf(x4.x * r4.x, __cosf(fmaf(dtf, w4.x, b4.x)) * wgt, acc.x);
    acc.y = fmaf(x4.y * r4.y, __cosf(fmaf(dtf, w4.y, b4.y)) * wgt, acc.y);
    acc.z = fmaf(x4.z * r4.z, __cosf(fmaf(dtf, w4.z, b4.z)) * wgt, acc.z);
    acc.w = fmaf(x4.w * r4.w, __cosf(fmaf(dtf, w4.w, b4.w)) * wgt, acc.w);
  }
  *(float4*)&aggbuf[wv][b][q4i * 4] = acc;
  int c = lane;
  const float* WT = ws + OFF_LINT + 2 * DD * DD;  // l = 1
  const float* X1 = ws + OFF_X + (size_t)w * XSZ;
  float* X2 = ws + OFF_X2 + (size_t)w * XSZ;
  const unsigned char* fb = (const unsigned char*)(wsi + IOFF_FLG) + (size_t)w * NN * 4;
  float sc = lns[DD + c], bc = lnb[DD + c];
  float hcx = ws[OFF_YC + 64 + c];
  float ycc = ws[OFF_YC + c];
#pragma unroll 1
  for (int r = 0; r < NB; ++r) {
    if (!((needw >> (r * 8)) & 0xffu)) continue;
    int f = fb[(size_t)n * 4 + r];
    float a = linb[DD + c];
    if (f) {
      const float* xr = X1 + ((size_t)n * NB + r) * DD;
#pragma unroll 8
      for (int k = 0; k < DD; ++k) a = fmaf(xr[k], WT[k * DD + c], a);
    } else {
      a += hcx;
    }
#pragma unroll 8
    for (int k = 0; k < DD; ++k)
      a = fmaf(aggbuf[wv][r][k], WT[(DD + k) * DD + c], a);
    float s = a;
    for (int m = 1; m < 64; m <<= 1) s += __shfl_xor(s, m);
    float mean = s * (1.f / 64.f);
    float cv = a - mean;
    float vv = cv * cv;
    for (int m = 1; m < 64; m <<= 1) vv += __shfl_xor(vv, m);
    vv *= (1.f / 64.f);
    float y = cv * __frsqrt_rn(vv + LN_EPS) * sc + bc;
    y = fmaxf(y, 0.f);
    float xo = f ? X1[((size_t)n * NB + r) * DD + c] : ycc;
    X2[((size_t)n * NB + r) * DD + c] = xo + y;
  }
}

// ------- transformer + final MLP, with fused l2-tail prefix (overlapped with f=0
//         staging loads); RPB=2, 98KB LDS (1 blk/CU), register-batched staging -------
#define NT (RPB * 192)
#define NIT ((4096 + NT - 1) / NT)
__global__ __launch_bounds__(NT) void k_xform(
    const float* __restrict__ tw, const float* __restrict__ tb,
    const float* __restrict__ pe, const float* __restrict__ linb,
    const float* __restrict__ lns, const float* __restrict__ lnb,
    const float* __restrict__ wq, const float* __restrict__ wk,
    const float* __restrict__ wv, const float* __restrict__ wo,
    const float* __restrict__ ffw1, const float* __restrict__ ffb1,
    const float* __restrict__ ffw2, const float* __restrict__ ffb2,
    const float* __restrict__ fln1s, const float* __restrict__ fln1b,
    const float* __restrict__ fln2s, const float* __restrict__ fln2b,
    const float* __restrict__ m1w, const float* __restrict__ m1b,
    const float* __restrict__ m2w, const float* __restrict__ m2b,
    float* __restrict__ ws, float* __restrict__ out) {
  __shared__ float tok[RPB][NW][DD], kvb[RPB][NW][DD], vvb[RPB][NW][DD];
  __shared__ float hbuf[RPB][NW][NFFN];
  __shared__ float feat[RPB][2 * DD];
  __shared__ float red[RPB][2];
  __shared__ float4 wbuf4[4352 + 1024];  // ~98KB block LDS -> 1 block/CU
  int tid = threadIdx.x;
  int rr = tid / 192;
  int t192 = tid - rr * 192;
  int tk = t192 >> 6, d = t192 & 63;
  int row = blockIdx.x * RPB + rr, b = row / NNEG;
  const int* wsi = (const int*)ws;
  float4 tmp[NIT];

  // ---- pre-issue f=0 QKVO staging loads (overlap with ltail latency) ----
  {
    const float4* s0 = (const float4*)wq;
    const float4* s1 = (const float4*)wk;
    const float4* s2 = (const float4*)wv;
    const float4* s3 = (const float4*)wo;
#pragma unroll
    for (int u = 0; u < NIT; ++u) {
      int idx = tid + u * NT;
      if (idx < 4096) {
        int m = idx >> 10, rem = idx & 1023;
        const float4* s = (m == 0) ? s0 : (m == 1) ? s1 : (m == 2) ? s2 : s3;
        tmp[u] = s[rem];
      }
    }
  }

  // ---- fused l2 tail: wave (rr,tk) computes token (row, w = tk) ----
  {
    int w = tk;
    int t = wsi[OFF_TSW + row];  // row = b*NNEG + j
    int h0b = wsi[OFF_H0 + b];
    int li = wsi[IOFF_LIDX + (size_t)w * NN + t];
    int dg = wsi[IOFF_DEG + (size_t)w * LCAP + li];
    if (dg > SLOTS) dg = SLOTS;
    const int4* recs = ((const int4*)(wsi + IOFF_REC2)) + ((size_t)w * LCAP + li) * SLOTS;
    const float* rell = ws + OFF_RELI + (size_t)2 * NR * NB * DD;
    const float* twl = tw + 2 * NR * DD;
    const float* tbl = tb + 2 * NR * DD;
    const float* xw = ws + OFF_X2 + (size_t)w * XSZ;
    float acc = (t == h0b) ? ws[OFF_QUERY + b * DD + d] : 0.f;
    for (int e = 0; e < dg; ++e) {
      int4 rec = recs[e];
      int src = rec.x, et = rec.y;
      float dtf = __int_as_float(rec.z), wgt = __int_as_float(rec.w);
      float xv = xw[(size_t)src * (NB * DD) + b * DD + d];
      float rv = rell[(size_t)et * (NB * DD) + b * DD + d];
      float te = __cosf(fmaf(dtf, twl[et * DD + d], tbl[et * DD + d]));
      acc = fmaf(xv * rv, te * wgt, acc);
    }
    float xo = xw[(size_t)t * (NB * DD) + b * DD + d];
    // wave-private LDS handoff via kvb (rowx) / vvb (rowa); own slot only
    kvb[rr][tk][d] = xo;
    vvb[rr][tk][d] = acc;
    int c = d;
    const float* WT = ws + OFF_LINT + 2 * 2 * DD * DD;  // l = 2
    float hid = linb[2 * DD + c];
#pragma unroll 8
    for (int k = 0; k < DD; ++k) hid = fmaf(kvb[rr][tk][k], WT[k * DD + c], hid);
#pragma unroll 8
    for (int k = 0; k < DD; ++k) hid = fmaf(vvb[rr][tk][k], WT[(DD + k) * DD + c], hid);
    float s = hid;
    for (int m = 1; m < 64; m <<= 1) s += __shfl_xor(s, m);
    float mean = s * (1.f / 64.f);
    float cv = hid - mean;
    float vv2 = cv * cv;
    for (int m = 1; m < 64; m <<= 1) vv2 += __shfl_xor(vv2, m);
    vv2 *= (1.f / 64.f);
    float y = cv * __frsqrt_rn(vv2 + LN_EPS) * lns[2 * DD + c] + lnb[2 * DD + c];
    y = fmaxf(y, 0.f);
    tok[rr][tk][d] = xo + y + pe[w * DD + c];
  }

  for (int f = 0; f < NFL; ++f) {
    // ---- stage wq,wk,wv,wo as 4x [64][68] (f=0 loads pre-issued) ----
    if (f > 0) {
      const float4* s0 = (const float4*)(wq + (size_t)f * DD * DD);
      const float4* s1 = (const float4*)(wk + (size_t)f * DD * DD);
      const float4* s2 = (const float4*)(wv + (size_t)f * DD * DD);
      const float4* s3 = (const float4*)(wo + (size_t)f * DD * DD);
#pragma unroll
      for (int u = 0; u < NIT; ++u) {
        int idx = tid + u * NT;
        if (idx < 4096) {
          int m = idx >> 10, rem = idx & 1023;
          const float4* s = (m == 0) ? s0 : (m == 1) ? s1 : (m == 2) ? s2 : s3;
          tmp[u] = s[rem];
        }
      }
    }
#pragma unroll
    for (int u = 0; u < NIT; ++u) {
      int idx = tid + u * NT;
      if (idx < 4096) {
        int m = idx >> 10, rem = idx & 1023;
        wbuf4[(m * 64 + (rem >> 4)) * 17 + (rem & 15)] = tmp[u];
      }
    }
    __syncthreads();
    float qd = 0.f, kd = 0.f, vd = 0.f;
#pragma unroll
    for (int kk = 0; kk < 16; ++kk) {
      float4 tv = *(const float4*)&tok[rr][tk][4 * kk];
      float4 aq = wbuf4[(0 * 64 + d) * 17 + kk];
      float4 ak = wbuf4[(1 * 64 + d) * 17 + kk];
      float4 av = wbuf4[(2 * 64 + d) * 17 + kk];
      qd += tv.x * aq.x + tv.y * aq.y + tv.z * aq.z + tv.w * aq.w;
      kd += tv.x * ak.x + tv.y * ak.y + tv.z * ak.z + tv.w * ak.w;
      vd += tv.x * av.x + tv.y * av.y + tv.z * av.z + tv.w * av.w;
    }
    kvb[rr][tk][d] = kd;
    vvb[rr][tk][d] = vd;
    __syncthreads();
    float sc[NW];
#pragma unroll
    for (int j = 0; j < NW; ++j) {
      float p = qd * kvb[rr][j][d];
      p += __shfl_xor(p, 1);
      p += __shfl_xor(p, 2);
      p += __shfl_xor(p, 4);
      p += __shfl_xor(p, 8);
      sc[j] = p * 0.25f;
    }
    float mx = fmaxf(sc[0], fmaxf(sc[1], sc[2]));
    float e0 = expf(sc[0] - mx), e1 = expf(sc[1] - mx), e2 = expf(sc[2] - mx);
    float inv = 1.f / (e0 + e1 + e2);
    float od = (e0 * vvb[rr][0][d] + e1 * vvb[rr][1][d] + e2 * vvb[rr][2][d]) * inv;
    __syncthreads();
    kvb[rr][tk][d] = od;
    float ao = 0.f;
#pragma unroll
    for (int kk = 0; kk < 16; ++kk) {
      float4 ov = *(const float4*)&kvb[rr][tk][4 * kk];
      float4 w4 = wbuf4[(3 * 64 + d) * 17 + kk];
      ao += ov.x * w4.x + ov.y * w4.y + ov.z * w4.z + ov.w * w4.w;
    }
    float t1 = tok[rr][tk][d] + ao;
    float s = t1;
    for (int m = 1; m < 64; m <<= 1) s += __shfl_xor(s, m);
    float mean = s * (1.f / 64.f);
    float cv = t1 - mean;
    float v = cv * cv;
    for (int m = 1; m < 64; m <<= 1) v += __shfl_xor(v, m);
    v *= (1.f / 64.f);
    t1 = cv * __frsqrt_rn(v + LN_EPS) * fln1s[f * DD + d] + fln1b[f * DD + d];
    tok[rr][tk][d] = t1;
    __syncthreads();
    // ---- stage ffw1 [256][68] ----
    {
      const float4* s4 = (const float4*)(ffw1 + (size_t)f * NFFN * DD);
#pragma unroll
      for (int u = 0; u < NIT; ++u) {
        int idx = tid + u * NT;
        if (idx < 4096) tmp[u] = s4[idx];
      }
#pragma unroll
      for (int u = 0; u < NIT; ++u) {
        int idx = tid + u * NT;
        if (idx < 4096) wbuf4[(idx >> 4) * 17 + (idx & 15)] = tmp[u];
      }
    }
    __syncthreads();
    float h[4];
#pragma unroll
    for (int uu = 0; uu < 4; ++uu) h[uu] = ffb1[f * NFFN + d + 64 * uu];
#pragma unroll
    for (int kk = 0; kk < 16; ++kk) {
      float4 tv = *(const float4*)&tok[rr][tk][4 * kk];
      float4 w0 = wbuf4[(d + 0) * 17 + kk];
      float4 w1 = wbuf4[(d + 64) * 17 + kk];
      float4 w2 = wbuf4[(d + 128) * 17 + kk];
      float4 w3 = wbuf4[(d + 192) * 17 + kk];
      h[0] += tv.x * w0.x + tv.y * w0.y + tv.z * w0.z + tv.w * w0.w;
      h[1] += tv.x * w1.x + tv.y * w1.y + tv.z * w1.z + tv.w * w1.w;
      h[2] += tv.x * w2.x + tv.y * w2.y + tv.z * w2.z + tv.w * w2.w;
      h[3] += tv.x * w3.x + tv.y * w3.y + tv.z * w3.z + tv.w * w3.w;
    }
#pragma unroll
    for (int uu = 0; uu < 4; ++uu) hbuf[rr][tk][d + 64 * uu] = fmaxf(h[uu], 0.f);
    __syncthreads();
    // ---- stage ffw2 [64][260] ----
    {
      const float4* s4 = (const float4*)(ffw2 + (size_t)f * DD * NFFN);
#pragma unroll
      for (int u = 0; u < NIT; ++u) {
        int idx = tid + u * NT;
        if (idx < 4096) tmp[u] = s4[idx];
      }
#pragma unroll
      for (int u = 0; u < NIT; ++u) {
        int idx = tid + u * NT;
        if (idx < 4096) wbuf4[(idx >> 6) * 65 + (idx & 63)] = tmp[u];
      }
    }
    __syncthreads();
    float ff = ffb2[f * DD + d];
#pragma unroll 8
    for (int kk = 0; kk < 64; ++kk) {
      float4 hv = *(const float4*)&hbuf[rr][tk][4 * kk];
      float4 w4 = wbuf4[d * 65 + kk];
      ff += hv.x * w4.x + hv.y * w4.y + hv.z * w4.z + hv.w * w4.w;
    }
    float t2 = t1 + ff;
    s = t2;
    for (int m = 1; m < 64; m <<= 1) s += __shfl_xor(s, m);
    mean = s * (1.f / 64.f);
    cv = t2 - mean;
    v = cv * cv;
    for (int m = 1; m < 64; m <<= 1) v += __shfl_xor(v, m);
    v *= (1.f / 64.f);
    t2 = cv * __frsqrt_rn(v + LN_EPS) * fln2s[f * DD + d] + fln2b[f * DD + d];
    tok[rr][tk][d] = t2;
    __syncthreads();
  }
  if (tk == 2) {
    feat[rr][d] = tok[rr][2][d];
    feat[rr][DD + d] = ws[OFF_QUERY + b * DD + d];
  }
  {
    const float4* s4 = (const float4*)m1w;
#pragma unroll
    for (int u = 0; u < NIT; ++u) {
      int idx = tid + u * NT;
      if (idx < 4096) tmp[u] = s4[idx];
    }
#pragma unroll
    for (int u = 0; u < NIT; ++u) {
      int idx = tid + u * NT;
      if (idx < 4096) wbuf4[(idx >> 5) * 33 + (idx & 31)] = tmp[u];
    }
  }
  __syncthreads();
  float partial = 0.f;
  if (t192 < 2 * DD) {
    int hh = t192;
    float acc = m1b[hh];
#pragma unroll
    for (int kk = 0; kk < 32; ++kk) {
      float4 fv = *(const float4*)&feat[rr][4 * kk];
      float4 w4 = wbuf4[hh * 33 + kk];
      acc += fv.x * w4.x + fv.y * w4.y + fv.z * w4.z + fv.w * w4.w;
    }
    acc = fmaxf(acc, 0.f);
    partial = acc * m2w[hh];
  }
  for (int m = 1; m < 64; m <<= 1) partial += __shfl_xor(partial, m);
  if (d == 0 && tk < 2) red[rr][tk] = partial;
  __syncthreads();
  if (t192 == 0) out[row] = red[rr][0] + red[rr][1] + m2b[0];
}

extern "C" void kernel_launch(void* const* d_in, const int* in_sizes, int n_in,
                              void* d_out, int out_size, void* d_ws, size_t ws_size,
                              hipStream_t stream) {
  const int* qt = (const int*)d_in[0];
  const int* eidx = (const int*)d_in[1];
  const int* etype = (const int*)d_in[2];
  const int* etime = (const int*)d_in[3];
  const float* qemb = (const float*)d_in[4];
  const float* ew = (const float*)d_in[5];
  const float* rlw = (const float*)d_in[6];
  const float* rlb = (const float*)d_in[7];
  const float* tw = (const float*)d_in[8];
  const float* tb = (const float*)d_in[9];
  const float* linw = (const float*)d_in[10];
  const float* linb = (const float*)d_in[11];
  const float* lns = (const float*)d_in[12];
  const float* lnb = (const float*)d_in[13];
  const float* pe = (const float*)d_in[14];
  const float* wq = (const float*)d_in[15];
  const float* wk = (const float*)d_in[16];
  const float* wv = (const float*)d_in[17];
  const float* wo = (const float*)d_in[18];
  const float* ffw1 = (const float*)d_in[19];
  const float* ffb1 = (const float*)d_in[20];
  const float* ffw2 = (const float*)d_in[21];
  const float* ffb2 = (const float*)d_in[22];
  const float* fln1s = (const float*)d_in[23];
  const float* fln1b = (const float*)d_in[24];
  const float* fln2s = (const float*)d_in[25];
  const float* fln2b = (const float*)d_in[26];
  const float* m1w = (const float*)d_in[27];
  const float* m1b = (const float*)d_in[28];
  const float* m2w = (const float*)d_in[29];
  const float* m2b = (const float*)d_in[30];
  float* ws = (float*)d_ws;
  float* out = (float*)d_out;

  k_prep<<<97 + 40, 256, 0, stream>>>(qt, qemb, linw, linb, lns, lnb, ws);
  k_mint<<<(NE + 255) / 256, 256, 0, stream>>>(etime, ws);
  k_relhist<<<dim3(441, NW), 256, 0, stream>>>(rlw, rlb, eidx, etype, etime, ew, ws);
  k_build<<<dim3(391 + L0NCAP / 4, NW), 256, 0, stream>>>(eidx, etype, etime, ew, tw, tb,
                                                          linb, lns, lnb, ws);
  k_l1<<<dim3(LCAP / 4, NW), 256, 0, stream>>>(tw, tb, linb, lns, lnb, ws);
  k_xform<<<NB * NNEG / RPB, NT, 0, stream>>>(tw, tb, pe, linb, lns, lnb, wq, wk, wv, wo,
                                              ffw1, ffb1, ffw2, ffb2, fln1s, fln1b,
                                              fln2s, fln2b, m1w, m1b, m2w, m2b, ws, out);
}

// Round 22
// 146.769 us; speedup vs baseline: 1.0353x; 1.0353x over previous
//
#include <hip/hip_runtime.h>
#include <hip/hip_bf16.h>
#include <cmath>

#define NB 4
#define NNEG 33
#define NN 10000
#define NE 100000
#define NW 3
#define DD 64
#define NL 3
#define NR 200
#define NFL 2
#define NFFN 256
#define LN_EPS 1e-5f
#define RPB 2
#define XSZ (NB*NN*DD)
#define LCAP 2048
#define SLOTS 64
#define L0ECAP 1024
#define L0NCAP 512

// ---- ws layout (float offsets) ----
#define OFF_QUERY 0
#define OFF_H0    256
#define OFF_TSW   288
#define OFF_MINT  448
#define OFF_RELI  512                                 // NL*NR*NB*DD
#define OFF_LINT  (OFF_RELI + NL*NR*NB*DD)            // NL*2*DD*DD
#define OFF_X     (OFF_LINT + NL*2*DD*DD)             // NW*XSZ (x1, sparse-valid)
#define OFF_X2    (OFF_X + NW*XSZ)                    // NW*XSZ (x2, needed-valid)
#define OFF_TOK   (OFF_X2 + NW*XSZ)                   // NB*NNEG*NW*DD
#define OFF_YC    (OFF_TOK + NB*NNEG*NW*DD)           // 64 yc + 64 hcx
// int offsets
#define IOFF_FLG  (OFF_YC + 128)                      // NW*NN words (byte per (n,b))
#define IOFF_NEED (IOFF_FLG + NW*NN)                  // NW*NN words
#define IOFF_CNT  (IOFF_NEED + NW*NN)                 // NW
#define IOFF_LIST (IOFF_CNT + NW)                     // NW*LCAP
#define IOFF_L0EC (IOFF_LIST + NW*LCAP)               // NW
#define IOFF_L0NC (IOFF_L0EC + NW)                    // NW
#define IOFF_L0EL (((IOFF_L0NC + NW) + 3) & ~3)       // NW*L0ECAP*4, 16B aligned
#define IOFF_L0ND (IOFF_L0EL + NW*L0ECAP*4)           // NW*L0NCAP
#define IOFF_TAILF (IOFF_L0ND + NW*L0NCAP)            // NN words (b-mask, shared w)
#define IOFF_LIDX (IOFF_TAILF + NN)                   // NW*NN (list index per needed node)
#define IOFF_DEG  (IOFF_LIDX + NW*NN)                 // NW*LCAP cursors
#define IOFF_REC2 (((IOFF_DEG + NW*LCAP) + 3) & ~3)   // NW*LCAP*SLOTS*4 ints, 16B aligned

// ---------------- prep (+ yconst/hcx) + transpose + tailf zero ----------------
__global__ void k_prep(const int* __restrict__ qt, const float* __restrict__ qemb,
                       const float* __restrict__ linw, const float* __restrict__ linb,
                       const float* __restrict__ lns, const float* __restrict__ lnb,
                       float* __restrict__ ws) {
  int bx = blockIdx.x;
  if (bx >= 97) {  // zero tailf
    int idx = (bx - 97) * 256 + threadIdx.x;
    if (idx < NN) ((int*)ws)[IOFF_TAILF + idx] = 0;
    return;
  }
  if (bx > 0) {  // transpose: linT[l][k][c] = lin_w[l][c][k]
    int idx = (bx - 1) * 256 + threadIdx.x;
    if (idx < NL * 2 * DD * DD) {
      int l = idx / (2 * DD * DD), r = idx % (2 * DD * DD), k = r / DD, c = r % DD;
      ws[OFF_LINT + idx] = linw[(l * DD + c) * 2 * DD + k];
    }
    return;
  }
  int tid = threadIdx.x;
  if (tid < NB * DD) {
    int b = tid / DD, d = tid % DD;
    int h0 = qt[(b * NNEG + 0) * 3 + 0];
    bool itn = true;
    for (int j = 1; j < NNEG; ++j) itn = itn && (qt[(b * NNEG + j) * 3 + 0] == h0);
    int r0 = qt[(b * NNEG + 0) * 3 + 1] + (itn ? 0 : NR / 2);
    ws[OFF_QUERY + b * DD + d] = qemb[r0 * DD + d];
    if (d == 0) {
      int t0 = qt[(b * NNEG + 0) * 3 + 2];
      ((int*)ws)[OFF_H0 + b] = itn ? h0 : t0;
    }
  }
  if (tid < NB * NNEG) {
    int b = tid / NNEG, j = tid % NNEG;
    int h0 = qt[(b * NNEG + 0) * 3 + 0];
    bool itn = true;
    for (int jj = 1; jj < NNEG; ++jj) itn = itn && (qt[(b * NNEG + jj) * 3 + 0] == h0);
    int h = qt[(b * NNEG + j) * 3 + 0], t = qt[(b * NNEG + j) * 3 + 2];
    ((int*)ws)[OFF_TSW + tid] = itn ? t : h;
  }
  if (tid == 0) ((int*)ws)[OFF_MINT] = 0x7fffffff;
  if (tid < 64) {
    int d = tid;
    float v = linb[d];  // l = 0 bias
    float s = v;
    for (int m = 1; m < 64; m <<= 1) s += __shfl_xor(s, m);
    float mean = s * (1.f / 64.f);
    float cv = v - mean;
    float vv = cv * cv;
    for (int m = 1; m < 64; m <<= 1) vv += __shfl_xor(vv, m);
    vv *= (1.f / 64.f);
    float y = cv * __frsqrt_rn(vv + LN_EPS) * lns[d] + lnb[d];
    y = fmaxf(y, 0.f);
    ws[OFF_YC + d] = y;
    const float* wr = linw + (size_t)DD * 2 * DD + (size_t)d * 2 * DD;  // l=1 row d
    float acc = 0.f;
    for (int k = 0; k < 64; ++k) acc = fmaf(__shfl(y, k), wr[k], acc);
    ws[OFF_YC + 64 + d] = acc;
  }
}

// ---------------- min over edge_time[0] + zero need/flg/deg/counters + tail mark ------
__global__ void k_mint(const int* __restrict__ etime, float* __restrict__ ws) {
  int i = blockIdx.x * blockDim.x + threadIdx.x;
  int* wsi = (int*)ws;
  if (i < NW * NN) wsi[IOFF_NEED + i] = 0;
  if (i < NW * NN) wsi[IOFF_FLG + i] = 0;
  if (i < NW * LCAP) wsi[IOFF_DEG + i] = 0;
  if (i < NW) {
    wsi[IOFF_CNT + i] = 0;
    wsi[IOFF_L0EC + i] = 0;
    wsi[IOFF_L0NC + i] = 0;
  }
  if (i < NB * NNEG) {  // mark tailflag (tailf zeroed in k_prep)
    int b = i / NNEG;
    int t = wsi[OFF_TSW + i];
    atomicOr((unsigned int*)&wsi[IOFF_TAILF + t], 1u << (b * 8));
  }
  int v = (i < NE) ? etime[i] : 0x7fffffff;
  for (int m = 1; m < 64; m <<= 1) v = min(v, __shfl_xor(v, m));
  if ((threadIdx.x & 63) == 0) atomicMin(&wsi[OFF_MINT], v);
}

// ------- merged: rel (bx<50) | single edge pass: edge0 + needscan (50..440) ----------
__global__ void k_relhist(const float* __restrict__ rlw, const float* __restrict__ rlb,
                          const int* __restrict__ eidx, const int* __restrict__ etype,
                          const int* __restrict__ etime, const float* __restrict__ eweight,
                          float* __restrict__ ws) {
  int bx = blockIdx.x;
  int* wsi = (int*)ws;
  if (bx < 50) {  // ---- rel: l = blockIdx.y ----
    int l = blockIdx.y;
    int rd = bx * 256 + threadIdx.x;
    const float4* wrow = (const float4*)(rlw + ((size_t)(l * NR * DD + rd)) * DD);
    float4 wreg[16];
#pragma unroll
    for (int kk = 0; kk < 16; ++kk) wreg[kk] = wrow[kk];
    float bias = rlb[l * NR * DD + rd];
    int r = rd >> 6, d = rd & 63;
    for (int b = 0; b < NB; ++b) {
      const float4* q4 = (const float4*)(ws + OFF_QUERY + b * DD);
      float acc = 0.f;
#pragma unroll
      for (int kk = 0; kk < 16; ++kk) {
        float4 q = q4[kk];
        acc += q.x * wreg[kk].x + q.y * wreg[kk].y + q.z * wreg[kk].z + q.w * wreg[kk].w;
      }
      ws[OFF_RELI + (size_t)(l * NR + r) * (NB * DD) + b * DD + d] = acc + bias;
    }
    return;
  }
  int w = blockIdx.y;
  unsigned int* flgw = (unsigned int*)(wsi + IOFF_FLG) + (size_t)w * NN;
  unsigned int* needw = (unsigned int*)(wsi + IOFF_NEED) + (size_t)w * NN;
  int* l0nc = wsi + IOFF_L0NC + w;
  int* l0nd = wsi + IOFF_L0ND + w * L0NCAP;
  int* cnt = wsi + IOFF_CNT + w;
  int* list = wsi + IOFF_LIST + (size_t)w * LCAP;
  int* lidx = wsi + IOFF_LIDX + (size_t)w * NN;
  if (bx == 50) {  // one-offs: h0 flag init + tails need-init
    if (threadIdx.x < NB) {
      int b = threadIdx.x;
      int h0b = wsi[OFF_H0 + b];
      unsigned int old = atomicOr(&flgw[h0b], 1u << (b * 8));
      if (old == 0u) {
        int p = atomicAdd(l0nc, 1);
        if (p < L0NCAP) l0nd[p] = h0b;
      }
    }
    if (threadIdx.x >= 64 && threadIdx.x < 64 + NB * NNEG) {
      int i = threadIdx.x - 64;
      int b = i / NNEG;
      int t = wsi[OFF_TSW + i];
      unsigned int old = atomicOr(&needw[t], 1u << (b * 8));
      if (old == 0u) {
        int p = atomicAdd(cnt, 1);
        if (p < LCAP) {
          list[p] = t;
          lidx[t] = p;
        }
      }
    }
  }
  int e = (bx - 50) * 256 + threadIdx.x;
  if (e >= NE) return;
  int src = eidx[(w * 2 + 0) * NE + e];
  int dst = eidx[(w * 2 + 1) * NE + e];
  // ---- edge0: src in {h0} ----
  int h00 = wsi[OFF_H0 + 0], h01 = wsi[OFF_H0 + 1];
  int h02 = wsi[OFF_H0 + 2], h03 = wsi[OFF_H0 + 3];
  int mask =
      (src == h00) | ((src == h01) << 1) | ((src == h02) << 2) | ((src == h03) << 3);
  if (mask) {
    unsigned int fm = ((mask & 1) ? 0x1u : 0u) | ((mask & 2) ? 0x100u : 0u) |
                      ((mask & 4) ? 0x10000u : 0u) | ((mask & 8) ? 0x1000000u : 0u);
    unsigned int old = atomicOr(&flgw[dst], fm);
    if (old == 0u) {
      int p = atomicAdd(l0nc, 1);
      if (p < L0NCAP) l0nd[p] = dst;
    }
    float dt = (float)etime[w * NE + e] - (float)wsi[OFF_MINT];
    int p = atomicAdd(wsi + IOFF_L0EC + w, 1);
    if (p < L0ECAP) {
      int4 ent;
      ent.x = dst;
      ent.y = etype[w * NE + e] | (mask << 16);
      ent.z = __float_as_int(dt);
      ent.w = __float_as_int(eweight[w * NE + e]);
      ((int4*)(wsi + IOFF_L0EL))[(size_t)w * L0ECAP + p] = ent;
    }
  }
  // ---- needscan: dst is tail -> mark src needed ----
  unsigned int tf = ((const unsigned int*)(wsi + IOFF_TAILF))[dst];
  if (tf) {
    unsigned int old = atomicOr(&needw[src], tf);
    if (old == 0u) {
      int p = atomicAdd(cnt, 1);
      if (p < LCAP) {
        list[p] = src;
        lidx[src] = p;
      }
    }
  }
}

// ---------------- merged: slot-list build (bx<391) | l0 compute (bx>=391) -------------
__global__ __launch_bounds__(256) void k_build(const int* __restrict__ eidx,
                                               const int* __restrict__ etype,
                                               const int* __restrict__ etime,
                                               const float* __restrict__ eweight,
                                               const float* __restrict__ tw,
                                               const float* __restrict__ tb,
                                               const float* __restrict__ linb,
                                               const float* __restrict__ lns,
                                               const float* __restrict__ lnb,
                                               float* __restrict__ ws) {
  __shared__ float aggbuf[4][NB][DD];
  int bx = blockIdx.x, w = blockIdx.y;
  int* wsi = (int*)ws;
  if (bx < 391) {  // ---- append needed-dst edges into per-node slot lists ----
    int e = bx * 256 + threadIdx.x;
    if (e >= NE) return;
    int dst = eidx[(w * 2 + 1) * NE + e];
    unsigned int nd = ((const unsigned int*)(wsi + IOFF_NEED))[(size_t)w * NN + dst];
    if (nd == 0u) return;
    int li = wsi[IOFF_LIDX + (size_t)w * NN + dst];
    int slot = atomicAdd(&wsi[IOFF_DEG + (size_t)w * LCAP + li], 1);
    if (slot < SLOTS) {
      float dt = (float)etime[w * NE + e] - (float)wsi[OFF_MINT];
      int4 rec;
      rec.x = eidx[(w * 2 + 0) * NE + e];
      rec.y = etype[w * NE + e];
      rec.z = __float_as_int(dt);
      rec.w = __float_as_int(eweight[w * NE + e]);
      ((int4*)(wsi + IOFF_REC2))[((size_t)w * LCAP + li) * SLOTS + slot] = rec;
    }
    return;
  }
  // ---- l0 compute: worklist of flagged nodes -> agg + gemm -> X1 ----
  int lane = threadIdx.x & 63;
  int wv = threadIdx.x >> 6;
  int b = lane >> 4;
  int q4i = lane & 15;
  int cnt = wsi[IOFF_L0NC + w];
  if (cnt > L0NCAP) cnt = L0NCAP;
  int idx = (bx - 391) * 4 + wv;
  if (idx >= cnt) return;  // no barriers below
  int n = wsi[IOFF_L0ND + w * L0NCAP + idx];
  unsigned int flagword = ((const unsigned int*)(wsi + IOFF_FLG))[(size_t)w * NN + n];
  int h0b = wsi[OFF_H0 + b];
  float4 q4b = ((const float4*)(ws + OFF_QUERY))[lane];
  float4 acc;
  if (n == h0b) acc = q4b;
  else { acc.x = 0.f; acc.y = 0.f; acc.z = 0.f; acc.w = 0.f; }
  int ec = wsi[IOFF_L0EC + w];
  if (ec > L0ECAP) ec = L0ECAP;
  const int4* el = ((const int4*)(wsi + IOFF_L0EL)) + (size_t)w * L0ECAP;
  const float4* RELI4 = (const float4*)(ws + OFF_RELI);  // l = 0
  const float4* TW4 = (const float4*)tw;
  const float4* TB4 = (const float4*)tb;
  for (int j = 0; j < ec; ++j) {
    int4 ent = el[j];
    if (ent.x != n) continue;
    int et = ent.y & 0xffff;
    int mask = ent.y >> 16;
    float dtf = __int_as_float(ent.z);
    float wgt = ((mask >> b) & 1) ? __int_as_float(ent.w) : 0.f;
    float4 r4 = RELI4[et * 64 + lane];
    float4 w4 = TW4[et * 16 + q4i];
    float4 b4 = TB4[et * 16 + q4i];
    acc.x = fmaf(q4b.x * r4.x, __cosf(fmaf(dtf, w4.x, b4.x)) * wgt, acc.x);
    acc.y = fmaf(q4b.y * r4.y, __cosf(fmaf(dtf, w4.y, b4.y)) * wgt, acc.y);
    acc.z = fmaf(q4b.z * r4.z, __cosf(fmaf(dtf, w4.z, b4.z)) * wgt, acc.z);
    acc.w = fmaf(q4b.w * r4.w, __cosf(fmaf(dtf, w4.w, b4.w)) * wgt, acc.w);
  }
  *(float4*)&aggbuf[wv][b][q4i * 4] = acc;
  int c = lane;
  const float* WT = ws + OFF_LINT;  // l = 0
  float* X1 = ws + OFF_X + (size_t)w * XSZ;
  float sc = lns[c], bc = lnb[c];
#pragma unroll 1
  for (int r = 0; r < NB; ++r) {
    if (!((flagword >> (r * 8)) & 0xffu)) continue;
    int h0r = wsi[OFF_H0 + r];
    float a = linb[c];
    if (n == h0r) {
      const float4* q4 = (const float4*)(ws + OFF_QUERY + r * DD);
      for (int kk = 0; kk < 16; ++kk) {
        float4 qv = q4[kk];
        a = fmaf(qv.x, WT[(4 * kk + 0) * DD + c], a);
        a = fmaf(qv.y, WT[(4 * kk + 1) * DD + c], a);
        a = fmaf(qv.z, WT[(4 * kk + 2) * DD + c], a);
        a = fmaf(qv.w, WT[(4 * kk + 3) * DD + c], a);
      }
    }
#pragma unroll 8
    for (int k = 0; k < DD; ++k)
      a = fmaf(aggbuf[wv][r][k], WT[(DD + k) * DD + c], a);
    float s = a;
    for (int m = 1; m < 64; m <<= 1) s += __shfl_xor(s, m);
    float mean = s * (1.f / 64.f);
    float cv = a - mean;
    float vv = cv * cv;
    for (int m = 1; m < 64; m <<= 1) vv += __shfl_xor(vv, m);
    vv *= (1.f / 64.f);
    float y = cv * __frsqrt_rn(vv + LN_EPS) * sc + bc;
    y = fmaxf(y, 0.f);
    float xo = (n == h0r) ? ws[OFF_QUERY + r * DD + c] : 0.f;
    X1[((size_t)n * NB + r) * DD + c] = xo + y;
  }
}

// ---------------- l1 fused, worklist-driven -> X2 (slot lists) ----------------
__global__ __launch_bounds__(256) void k_l1(const float* __restrict__ tw,
                                            const float* __restrict__ tb,
                                            const float* __restrict__ linb,
                                            const float* __restrict__ lns,
                                            const float* __restrict__ lnb,
                                            float* __restrict__ ws) {
  __shared__ float aggbuf[4][NB][DD];
  int w = blockIdx.y;
  const int* wsi = (const int*)ws;
  int cnt = wsi[IOFF_CNT + w];
  if (cnt > LCAP) cnt = LCAP;
  int wv = threadIdx.x >> 6;
  int idx = blockIdx.x * 4 + wv;
  if (idx >= cnt) return;  // per-wave exit; no barriers
  int n = wsi[IOFF_LIST + (size_t)w * LCAP + idx];
  int lane = threadIdx.x & 63;
  int b = lane >> 4;
  int q4i = lane & 15;
  unsigned int needw = ((const unsigned int*)(wsi + IOFF_NEED))[(size_t)w * NN + n];
  int dg = wsi[IOFF_DEG + (size_t)w * LCAP + idx];
  dg = __builtin_amdgcn_readfirstlane(dg > SLOTS ? SLOTS : dg);
  const int4* recs = ((const int4*)(wsi + IOFF_REC2)) + ((size_t)w * LCAP + idx) * SLOTS;
  const float4* X14 = (const float4*)(ws + OFF_X + (size_t)w * XSZ);
  const float4* RELI4 = (const float4*)(ws + OFF_RELI) + (size_t)1 * NR * 64;
  const float4* TW4 = (const float4*)(tw + (size_t)1 * NR * DD);
  const float4* TB4 = (const float4*)(tb + (size_t)1 * NR * DD);
  const unsigned int* xflg = (const unsigned int*)(wsi + IOFF_FLG) + (size_t)w * NN;
  int h0b = wsi[OFF_H0 + b];
  float4 q4b = ((const float4*)(ws + OFF_QUERY))[lane];
  float4 yc4 = ((const float4*)(ws + OFF_YC))[q4i];
  float4 acc;
  if (n == h0b) acc = q4b;
  else { acc.x = 0.f; acc.y = 0.f; acc.z = 0.f; acc.w = 0.f; }
  for (int j = 0; j < dg; ++j) {
    int4 rec = recs[j];
    int src = rec.x, et = rec.y;
    float dtf = __int_as_float(rec.z), wgt = __int_as_float(rec.w);
    unsigned int fw = xflg[src];
    float4 x4;
    if (fw == 0u) {
      x4 = yc4;
    } else {
      int myf = (fw >> (b * 8)) & 0xff;
      if (myf) x4 = X14[(size_t)src * 64 + lane];
      else x4 = yc4;
    }
    float4 r4 = RELI4[et * 64 + lane];
    float4 w4 = TW4[et * 16 + q4i];
    float4 b4 = TB4[et * 16 + q4i];
    acc.x = fmaf(x4.x * r4.x, __cosf(fmaf(dtf, w4.x, b4.x)) * wgt, acc.x);
    acc.y = fmaf(x4.y * r4.y, __cosf(fmaf(dtf, w4.y, b4.y)) * wgt, acc.y);
    acc.z = fmaf(x4.z * r4.z, __cosf(fmaf(dtf, w4.z, b4.z)) * wgt, acc.z);
    acc.w = fmaf(x4.w * r4.w, __cosf(fmaf(dtf, w4.w, b4.w)) * wgt, acc.w);
  }
  *(float4*)&aggbuf[wv][b][q4i * 4] = acc;
  int c = lane;
  const float* WT = ws + OFF_LINT + 2 * DD * DD;  // l = 1
  const float* X1 = ws + OFF_X + (size_t)w * XSZ;
  float* X2 = ws + OFF_X2 + (size_t)w * XSZ;
  const unsigned char* fb = (const unsigned char*)(wsi + IOFF_FLG) + (size_t)w * NN * 4;
  float sc = lns[DD + c], bc = lnb[DD + c];
  float hcx = ws[OFF_YC + 64 + c];
  float ycc = ws[OFF_YC + c];
#pragma unroll 1
  for (int r = 0; r < NB; ++r) {
    if (!((needw >> (r * 8)) & 0xffu)) continue;
    int f = fb[(size_t)n * 4 + r];
    float a = linb[DD + c];
    if (f) {
      const float* xr = X1 + ((size_t)n * NB + r) * DD;
#pragma unroll 8
      for (int k = 0; k < DD; ++k) a = fmaf(xr[k], WT[k * DD + c], a);
    } else {
      a += hcx;
    }
#pragma unroll 8
    for (int k = 0; k < DD; ++k)
      a = fmaf(aggbuf[wv][r][k], WT[(DD + k) * DD + c], a);
    float s = a;
    for (int m = 1; m < 64; m <<= 1) s += __shfl_xor(s, m);
    float mean = s * (1.f / 64.f);
    float cv = a - mean;
    float vv = cv * cv;
    for (int m = 1; m < 64; m <<= 1) vv += __shfl_xor(vv, m);
    vv *= (1.f / 64.f);
    float y = cv * __frsqrt_rn(vv + LN_EPS) * sc + bc;
    y = fmaxf(y, 0.f);
    float xo = f ? X1[((size_t)n * NB + r) * DD + c] : ycc;
    X2[((size_t)n * NB + r) * DD + c] = xo + y;
  }
}

// ---------------- l=2 tail-only -> TOK (slot lists) ----------------
__global__ __launch_bounds__(256) void k_ltail(const float* __restrict__ tw,
                                               const float* __restrict__ tb,
                                               const float* __restrict__ pe,
                                               const float* __restrict__ linb,
                                               const float* __restrict__ lns,
                                               const float* __restrict__ lnb,
                                               float* __restrict__ ws) {
  __shared__ float rowx[4][DD], rowa[4][DD];
  int b = threadIdx.x >> 6, d = threadIdx.x & 63;
  int j = blockIdx.x, w = blockIdx.y;
  const int* wsi = (const int*)ws;
  int t = wsi[OFF_TSW + b * NNEG + j];
  int h0b = wsi[OFF_H0 + b];
  int li = wsi[IOFF_LIDX + (size_t)w * NN + t];
  int dg = wsi[IOFF_DEG + (size_t)w * LCAP + li];
  if (dg > SLOTS) dg = SLOTS;
  const int4* recs = ((const int4*)(wsi + IOFF_REC2)) + ((size_t)w * LCAP + li) * SLOTS;
  const float* rell = ws + OFF_RELI + (size_t)2 * NR * NB * DD;
  const float* twl = tw + 2 * NR * DD;
  const float* tbl = tb + 2 * NR * DD;
  const float* xw = ws + OFF_X2 + (size_t)w * XSZ;
  float acc = (t == h0b) ? ws[OFF_QUERY + b * DD + d] : 0.f;
  for (int e = 0; e < dg; ++e) {
    int4 rec = recs[e];
    int src = rec.x, et = rec.y;
    float dtf = __int_as_float(rec.z), wgt = __int_as_float(rec.w);
    float xv = xw[(size_t)src * (NB * DD) + b * DD + d];
    float rv = rell[(size_t)et * (NB * DD) + b * DD + d];
    float te = __cosf(fmaf(dtf, twl[et * DD + d], tbl[et * DD + d]));
    acc = fmaf(xv * rv, te * wgt, acc);
  }
  float xo = xw[(size_t)t * (NB * DD) + b * DD + d];
  rowa[b][d] = acc;
  rowx[b][d] = xo;
  int c = d;
  const float* WT = ws + OFF_LINT + 2 * 2 * DD * DD;  // l = 2
  float hid = linb[2 * DD + c];
#pragma unroll 8
  for (int k = 0; k < DD; ++k) hid = fmaf(rowx[b][k], WT[k * DD + c], hid);
#pragma unroll 8
  for (int k = 0; k < DD; ++k) hid = fmaf(rowa[b][k], WT[(DD + k) * DD + c], hid);
  float s = hid;
  for (int m = 1; m < 64; m <<= 1) s += __shfl_xor(s, m);
  float mean = s * (1.f / 64.f);
  float cv = hid - mean;
  float vv = cv * cv;
  for (int m = 1; m < 64; m <<= 1) vv += __shfl_xor(vv, m);
  vv *= (1.f / 64.f);
  float y = cv * __frsqrt_rn(vv + LN_EPS) * lns[2 * DD + c] + lnb[2 * DD + c];
  y = fmaxf(y, 0.f);
  ws[OFF_TOK + (b * NNEG + j) * NW * DD + w * DD + c] = xo + y + pe[w * DD + c];
}

// ---------------- transformer + final MLP (round-13 structure, RPB=2) -----------------
__global__ __launch_bounds__(RPB * 192) void k_xform(
    const float* __restrict__ wq, const float* __restrict__ wk,
    const float* __restrict__ wv, const float* __restrict__ wo,
    const float* __restrict__ ffw1, const float* __restrict__ ffb1,
    const float* __restrict__ ffw2, const float* __restrict__ ffb2,
    const float* __restrict__ fln1s, const float* __restrict__ fln1b,
    const float* __restrict__ fln2s, const float* __restrict__ fln2b,
    const float* __restrict__ m1w, const float* __restrict__ m1b,
    const float* __restrict__ m2w, const float* __restrict__ m2b,
    float* __restrict__ ws, float* __restrict__ out) {
  __shared__ float tok[RPB][NW][DD], kvb[RPB][NW][DD], vvb[RPB][NW][DD];
  __shared__ float hbuf[RPB][NW][NFFN];
  __shared__ float feat[RPB][2 * DD];
  __shared__ float red[RPB][2];
  __shared__ float4 wbuf4[4352];
  const int NT = RPB * 192;
  int tid = threadIdx.x;
  int rr = tid / 192;
  int t192 = tid - rr * 192;
  int tk = t192 >> 6, d = t192 & 63;
  int row = blockIdx.x * RPB + rr, b = row / NNEG;
  tok[rr][tk][d] = ws[OFF_TOK + row * NW * DD + tk * DD + d];
  for (int f = 0; f < NFL; ++f) {
    {
      const float4* s0 = (const float4*)(wq + (size_t)f * DD * DD);
      const float4* s1 = (const float4*)(wk + (size_t)f * DD * DD);
      const float4* s2 = (const float4*)(wv + (size_t)f * DD * DD);
      const float4* s3 = (const float4*)(wo + (size_t)f * DD * DD);
      for (int idx = tid; idx < 4096; idx += NT) {
        int m = idx >> 10, rem = idx & 1023;
        int rrow = rem >> 4, c4 = rem & 15;
        const float4* s = (m == 0) ? s0 : (m == 1) ? s1 : (m == 2) ? s2 : s3;
        wbuf4[(m * 64 + rrow) * 17 + c4] = s[rem];
      }
    }
    __syncthreads();
    float qd = 0.f, kd = 0.f, vd = 0.f;
#pragma unroll
    for (int kk = 0; kk < 16; ++kk) {
      float4 tv = *(const float4*)&tok[rr][tk][4 * kk];
      float4 aq = wbuf4[(0 * 64 + d) * 17 + kk];
      float4 ak = wbuf4[(1 * 64 + d) * 17 + kk];
      float4 av = wbuf4[(2 * 64 + d) * 17 + kk];
      qd += tv.x * aq.x + tv.y * aq.y + tv.z * aq.z + tv.w * aq.w;
      kd += tv.x * ak.x + tv.y * ak.y + tv.z * ak.z + tv.w * ak.w;
      vd += tv.x * av.x + tv.y * av.y + tv.z * av.z + tv.w * av.w;
    }
    kvb[rr][tk][d] = kd;
    vvb[rr][tk][d] = vd;
    __syncthreads();
    float sc[NW];
#pragma unroll
    for (int j = 0; j < NW; ++j) {
      float p = qd * kvb[rr][j][d];
      p += __shfl_xor(p, 1);
      p += __shfl_xor(p, 2);
      p += __shfl_xor(p, 4);
      p += __shfl_xor(p, 8);
      sc[j] = p * 0.25f;
    }
    float mx = fmaxf(sc[0], fmaxf(sc[1], sc[2]));
    float e0 = expf(sc[0] - mx), e1 = expf(sc[1] - mx), e2 = expf(sc[2] - mx);
    float inv = 1.f / (e0 + e1 + e2);
    float od = (e0 * vvb[rr][0][d] + e1 * vvb[rr][1][d] + e2 * vvb[rr][2][d]) * inv;
    __syncthreads();
    kvb[rr][tk][d] = od;
    float ao = 0.f;
#pragma unroll
    for (int kk = 0; kk < 16; ++kk) {
      float4 ov = *(const float4*)&kvb[rr][tk][4 * kk];
      float4 w4 = wbuf4[(3 * 64 + d) * 17 + kk];
      ao += ov.x * w4.x + ov.y * w4.y + ov.z * w4.z + ov.w * w4.w;
    }
    float t1 = tok[rr][tk][d] + ao;
    float s = t1;
    for (int m = 1; m < 64; m <<= 1) s += __shfl_xor(s, m);
    float mean = s * (1.f / 64.f);
    float cv = t1 - mean;
    float v = cv * cv;
    for (int m = 1; m < 64; m <<= 1) v += __shfl_xor(v, m);
    v *= (1.f / 64.f);
    t1 = cv * __frsqrt_rn(v + LN_EPS) * fln1s[f * DD + d] + fln1b[f * DD + d];
    tok[rr][tk][d] = t1;
    __syncthreads();
    {
      const float4* s4 = (const float4*)(ffw1 + (size_t)f * NFFN * DD);
      for (int idx = tid; idx < 4096; idx += NT) {
        int rrow = idx >> 4, c4 = idx & 15;
        wbuf4[rrow * 17 + c4] = s4[idx];
      }
    }
    __syncthreads();
    float h[4];
#pragma unroll
    for (int uu = 0; uu < 4; ++uu) h[uu] = ffb1[f * NFFN + d + 64 * uu];
#pragma unroll
    for (int kk = 0; kk < 16; ++kk) {
      float4 tv = *(const float4*)&tok[rr][tk][4 * kk];
      float4 w0 = wbuf4[(d + 0) * 17 + kk];
      float4 w1 = wbuf4[(d + 64) * 17 + kk];
      float4 w2 = wbuf4[(d + 128) * 17 + kk];
      float4 w3 = wbuf4[(d + 192) * 17 + kk];
      h[0] += tv.x * w0.x + tv.y * w0.y + tv.z * w0.z + tv.w * w0.w;
      h[1] += tv.x * w1.x + tv.y * w1.y + tv.z * w1.z + tv.w * w1.w;
      h[2] += tv.x * w2.x + tv.y * w2.y + tv.z * w2.z + tv.w * w2.w;
      h[3] += tv.x * w3.x + tv.y * w3.y + tv.z * w3.z + tv.w * w3.w;
    }
#pragma unroll
    for (int uu = 0; uu < 4; ++uu) hbuf[rr][tk][d + 64 * uu] = fmaxf(h[uu], 0.f);
    __syncthreads();
    {
      const float4* s4 = (const float4*)(ffw2 + (size_t)f * DD * NFFN);
      for (int idx = tid; idx < 4096; idx += NT) {
        int rrow = idx >> 6, c4 = idx & 63;
        wbuf4[rrow * 65 + c4] = s4[idx];
      }
    }
    __syncthreads();
    float ff = ffb2[f * DD + d];
#pragma unroll 8
    for (int kk = 0; kk < 64; ++kk) {
      float4 hv = *(const float4*)&hbuf[rr][tk][4 * kk];
      float4 w4 = wbuf4[d * 65 + kk];
      ff += hv.x * w4.x + hv.y * w4.y + hv.z * w4.z + hv.w * w4.w;
    }
    float t2 = t1 + ff;
    s = t2;
    for (int m = 1; m < 64; m <<= 1) s += __shfl_xor(s, m);
    mean = s * (1.f / 64.f);
    cv = t2 - mean;
    v = cv * cv;
    for (int m = 1; m < 64; m <<= 1) v += __shfl_xor(v, m);
    v *= (1.f / 64.f);
    t2 = cv * __frsqrt_rn(v + LN_EPS) * fln2s[f * DD + d] + fln2b[f * DD + d];
    tok[rr][tk][d] = t2;
    __syncthreads();
  }
  if (tk == 2) {
    feat[rr][d] = tok[rr][2][d];
    feat[rr][DD + d] = ws[OFF_QUERY + b * DD + d];
  }
  {
    const float4* s4 = (const float4*)m1w;
    for (int idx = tid; idx < 4096; idx += NT) {
      int rrow = idx >> 5, c4 = idx & 31;
      wbuf4[rrow * 33 + c4] = s4[idx];
    }
  }
  __syncthreads();
  float partial = 0.f;
  if (t192 < 2 * DD) {
    int hh = t192;
    float acc = m1b[hh];
#pragma unroll
    for (int kk = 0; kk < 32; ++kk) {
      float4 fv = *(const float4*)&feat[rr][4 * kk];
      float4 w4 = wbuf4[hh * 33 + kk];
      acc += fv.x * w4.x + fv.y * w4.y + fv.z * w4.z + fv.w * w4.w;
    }
    acc = fmaxf(acc, 0.f);
    partial = acc * m2w[hh];
  }
  for (int m = 1; m < 64; m <<= 1) partial += __shfl_xor(partial, m);
  if (d == 0 && tk < 2) red[rr][tk] = partial;
  __syncthreads();
  if (t192 == 0) out[row] = red[rr][0] + red[rr][1] + m2b[0];
}

extern "C" void kernel_launch(void* const* d_in, const int* in_sizes, int n_in,
                              void* d_out, int out_size, void* d_ws, size_t ws_size,
                              hipStream_t stream) {
  const int* qt = (const int*)d_in[0];
  const int* eidx = (const int*)d_in[1];
  const int* etype = (const int*)d_in[2];
  const int* etime = (const int*)d_in[3];
  const float* qemb = (const float*)d_in[4];
  const float* ew = (const float*)d_in[5];
  const float* rlw = (const float*)d_in[6];
  const float* rlb = (const float*)d_in[7];
  const float* tw = (const float*)d_in[8];
  const float* tb = (const float*)d_in[9];
  const float* linw = (const float*)d_in[10];
  const float* linb = (const float*)d_in[11];
  const float* lns = (const float*)d_in[12];
  const float* lnb = (const float*)d_in[13];
  const float* pe = (const float*)d_in[14];
  const float* wq = (const float*)d_in[15];
  const float* wk = (const float*)d_in[16];
  const float* wv = (const float*)d_in[17];
  const float* wo = (const float*)d_in[18];
  const float* ffw1 = (const float*)d_in[19];
  const float* ffb1 = (const float*)d_in[20];
  const float* ffw2 = (const float*)d_in[21];
  const float* ffb2 = (const float*)d_in[22];
  const float* fln1s = (const float*)d_in[23];
  const float* fln1b = (const float*)d_in[24];
  const float* fln2s = (const float*)d_in[25];
  const float* fln2b = (const float*)d_in[26];
  const float* m1w = (const float*)d_in[27];
  const float* m1b = (const float*)d_in[28];
  const float* m2w = (const float*)d_in[29];
  const float* m2b = (const float*)d_in[30];
  float* ws = (float*)d_ws;
  float* out = (float*)d_out;

  k_prep<<<97 + 40, 256, 0, stream>>>(qt, qemb, linw, linb, lns, lnb, ws);
  k_mint<<<(NE + 255) / 256, 256, 0, stream>>>(etime, ws);
  k_relhist<<<dim3(441, NW), 256, 0, stream>>>(rlw, rlb, eidx, etype, etime, ew, ws);
  k_build<<<dim3(391 + L0NCAP / 4, NW), 256, 0, stream>>>(eidx, etype, etime, ew, tw, tb,
                                                          linb, lns, lnb, ws);
  k_l1<<<dim3(LCAP / 4, NW), 256, 0, stream>>>(tw, tb, linb, lns, lnb, ws);
  k_ltail<<<dim3(NNEG, NW), 256, 0, stream>>>(tw, tb, pe, linb, lns, lnb, ws);
  k_xform<<<NB * NNEG / RPB, RPB * 192, 0, stream>>>(wq, wk, wv, wo, ffw1, ffb1, ffw2,
                                                     ffb2, fln1s, fln1b, fln2s, fln2b,
                                                     m1w, m1b, m2w, m2b, ws, out);
}